// Round 19
// baseline (449.821 us; speedup 1.0000x reference)
//
#include <hip/hip_runtime.h>

typedef __attribute__((ext_vector_type(8))) short short8;
typedef __attribute__((ext_vector_type(4))) float f32x4;
typedef unsigned short u16;
typedef unsigned int u32;

#define DEVI __device__ __forceinline__

// barrier that does NOT drain vmcnt (keeps NT stores / prefetch in flight)
#define LGKM_BARRIER() do {                                         \
    asm volatile("s_waitcnt lgkmcnt(0)" ::: "memory");              \
    __builtin_amdgcn_sched_barrier(0);                              \
    __builtin_amdgcn_s_barrier();                                   \
    __builtin_amdgcn_sched_barrier(0);                              \
} while (0)

// round-to-nearest-even f32 -> bf16 bits
DEVI u16 f2bf(float f) {
    union { float f; u32 u; } v; v.f = f;
    u32 r = v.u + 0x7FFFu + ((v.u >> 16) & 1u);
    return (u16)(r >> 16);
}
DEVI float bf2f(u16 x) {
    union { u32 u; float f; } v; v.u = ((u32)x) << 16;
    return v.f;
}

// ---- fused pre-kernel: [blocks 0..63] embed+pos+leaky1; [64..] cvt3 ------
__global__ __launch_bounds__(256)
void pre_kernel(const int* __restrict__ x, const float* __restrict__ emb,
                const float* __restrict__ pos, const float* __restrict__ beta,
                u16* __restrict__ Aout,
                const float* __restrict__ wo, u16* __restrict__ WO, int nwo4,
                const float* __restrict__ w2, u16* __restrict__ W2, int nw24,
                const float* __restrict__ w3, u16* __restrict__ W3, int nw34) {
    if (blockIdx.x < 64) {
        __shared__ int xs[128];
        int gtid = blockIdx.x * 256 + threadIdx.x;
        int b = gtid >> 9;
        int h = gtid & 511;
        for (int i = threadIdx.x; i < 128; i += 256) xs[i] = x[i * 32 + b];
        __syncthreads();
        float be = beta[h];
        float mem = 0.f;
        for (int t0 = 0; t0 < 128; t0 += 8) {
            float e[8];
#pragma unroll
            for (int j = 0; j < 8; ++j)
                e[j] = emb[(size_t)xs[t0 + j] * 512 + h] + pos[(t0 + j) * 512 + h];
#pragma unroll
            for (int j = 0; j < 8; ++j) {
                mem = be * mem + e[j];
                Aout[(size_t)((t0 + j) * 32 + b) * 512 + h] = f2bf(mem);
            }
        }
    } else {
        int total = nwo4 + nw24 + nw34;
        int nb = gridDim.x - 64;
        int stride = nb * 256;
        for (int i = (blockIdx.x - 64) * 256 + threadIdx.x; i < total; i += stride) {
            const float* in; u16* out; int j = i;
            if (j < nwo4) { in = wo; out = WO; }
            else if ((j -= nwo4) < nw24) { in = w2; out = W2; }
            else { j -= nw24; in = w3; out = W3; }
            float4 v = reinterpret_cast<const float4*>(in)[j];
            ushort4 o;
            o.x = f2bf(v.x); o.y = f2bf(v.y); o.z = f2bf(v.z); o.w = f2bf(v.w);
            reinterpret_cast<ushort4*>(out)[j] = o;
        }
    }
}

// ---------------- leaky over bf16 input -> bf16 A ----------------
__global__ __launch_bounds__(64)
void leaky_bf16_kernel(const u16* __restrict__ in, const float* __restrict__ beta,
                       u16* __restrict__ Aout) {
    int gtid = blockIdx.x * 64 + threadIdx.x;
    int b = gtid >> 9;
    int h = gtid & 511;
    float be = beta[h];
    float mem = 0.f;
    for (int t0 = 0; t0 < 128; t0 += 8) {
        float v[8];
#pragma unroll
        for (int j = 0; j < 8; ++j)
            v[j] = bf2f(in[(size_t)((t0 + j) * 32 + b) * 512 + h]);
#pragma unroll
        for (int j = 0; j < 8; ++j) {
            mem = be * mem + v[j];
            Aout[(size_t)((t0 + j) * 32 + b) * 512 + h] = f2bf(mem);
        }
    }
}

// ---- 64x128 bf16 GEMM + bias + ReLU -> bf16 out (fc2/fc3) ----------------
__global__ __launch_bounds__(256)
void gemm_bt_64(const u16* __restrict__ A, const u16* __restrict__ B,
                const float* __restrict__ bias, u16* __restrict__ C,
                int M, int N, int K, int tiles_n) {
    __shared__ alignas(16) char smem[32 * 132 * 4];
    u16* As = (u16*)smem;
    u16* Bs = (u16*)(smem + 4096);
    float* Ep = (float*)smem;

    const int tid = threadIdx.x;
    int bm = blockIdx.x / tiles_n;
    int bn = blockIdx.x % tiles_n;
    const int wv = tid >> 6;
    const int lane = tid & 63;
    const int wr = wv >> 1, wc = wv & 1;
    const int lrow = lane & 15;
    const int kg = lane >> 4;
    const int kgx = kg ^ (lrow & 3);

    f32x4 acc[2][4];
#pragma unroll
    for (int i = 0; i < 2; ++i)
#pragma unroll
        for (int j = 0; j < 4; ++j) acc[i][j] = (f32x4){0.f, 0.f, 0.f, 0.f};

    const size_t rowb = (size_t)K * 2;
    const char* Ab = (const char*)A + (size_t)(bm * 64) * rowb;
    const char* Bb = (const char*)B + (size_t)(bn * 128) * rowb;

    float bv[4];
#pragma unroll
    for (int ni = 0; ni < 4; ++ni)
        bv[ni] = bias[bn * 128 + wc * 64 + ni * 16 + lrow];

    for (int k0 = 0; k0 < K; k0 += 32) {
        int k2 = k0 << 1;
        {
            int s = tid;
            int row = s >> 2, ls = s & 3;
            int gsl = ls ^ (row & 3);
            __builtin_amdgcn_global_load_lds(
                (const __attribute__((address_space(1))) void*)(Ab + (size_t)row * rowb + k2 + gsl * 16),
                (__attribute__((address_space(3))) void*)((char*)As + s * 16), 16, 0, 0);
        }
#pragma unroll
        for (int j = 0; j < 2; ++j) {
            int s = j * 256 + tid;
            int row = s >> 2, ls = s & 3;
            int gsl = ls ^ (row & 3);
            __builtin_amdgcn_global_load_lds(
                (const __attribute__((address_space(1))) void*)(Bb + (size_t)row * rowb + k2 + gsl * 16),
                (__attribute__((address_space(3))) void*)((char*)Bs + s * 16), 16, 0, 0);
        }
        __syncthreads();

        short8 a[2], b[4];
#pragma unroll
        for (int mi = 0; mi < 2; ++mi) {
            int rr = wr * 32 + mi * 16 + lrow;
            a[mi] = *(const short8*)((const char*)As + rr * 64 + kgx * 16);
        }
#pragma unroll
        for (int ni = 0; ni < 4; ++ni) {
            int rr = wc * 64 + ni * 16 + lrow;
            b[ni] = *(const short8*)((const char*)Bs + rr * 64 + kgx * 16);
        }
#pragma unroll
        for (int mi = 0; mi < 2; ++mi)
#pragma unroll
            for (int ni = 0; ni < 4; ++ni)
                acc[mi][ni] = __builtin_amdgcn_mfma_f32_16x16x32_bf16(a[mi], b[ni], acc[mi][ni], 0, 0, 0);
        __syncthreads();
    }

#pragma unroll
    for (int ch = 0; ch < 2; ++ch) {
        if (wr == ch) {
#pragma unroll
            for (int mi = 0; mi < 2; ++mi)
#pragma unroll
                for (int ni = 0; ni < 4; ++ni) {
                    int c = wc * 64 + ni * 16 + lrow;
                    f32x4 v = acc[mi][ni];
#pragma unroll
                    for (int j = 0; j < 4; ++j)
                        Ep[(mi * 16 + kg * 4 + j) * 132 + c] = fmaxf(v[j] + bv[ni], 0.f);
                }
        }
        __syncthreads();
#pragma unroll
        for (int rr = 0; rr < 8; ++rr) {
            int rl = wv * 8 + rr;
            int grow = bm * 64 + ch * 32 + rl;
            float lo = Ep[rl * 132 + lane * 2];
            float hi = Ep[rl * 132 + lane * 2 + 1];
            u32 pk = (u32)f2bf(lo) | ((u32)f2bf(hi) << 16);
            *(u32*)((char*)C + ((size_t)grow * N + bn * 128 + lane * 2) * 2) = pk;
        }
        if (ch < 1) __syncthreads();
    }
}

// ---------------- 128x256 bf16 GEMM, BK=32, tri-buffer, 2 blocks/CU (vocab)
// r17-best core (383.3us). CHANGED THIS ROUND (one line): tile order is
// bm-MAJOR (bn fastest) within each XCD chunk. Concurrent blocks now share a
// bm panel and span bn -> their NT stores cover complete contiguous output
// rows (~25.7MB/panel, per-XCD contiguous ~103MB regions) instead of 1KB
// segments strided 201KB apart across all 4096 rows. B is re-read per panel
// but stays L3-resident (51.6MB << 256MB; HBM touch once); the shared
// per-panel A-tile (128KB) is the L2-hit operand.
__global__ __launch_bounds__(512, 4)
void gemm_bt_v(const u16* __restrict__ A, const u16* __restrict__ B,
               const float* __restrict__ bias, float* __restrict__ C,
               int M, int N, int K, int tiles_m, int tiles_n) {
    extern __shared__ char smem[];   // 3 x 24576
    float* Ep = (float*)smem;        // [64][260] f32 = 66560 B

    const int tid = threadIdx.x;
    int nwg = tiles_m * tiles_n;
    int q = nwg >> 3, r = nwg & 7;
    int xcd = blockIdx.x & 7, idx = blockIdx.x >> 3;
    int wg = (xcd < r ? xcd * (q + 1) : r * (q + 1) + (xcd - r) * q) + idx;
    int bm = wg / tiles_n;           // bm-major: concurrent blocks share bm
    int bn = wg % tiles_n;

    const int wv = tid >> 6;
    const int lane = tid & 63;
    const int wr = wv >> 2;
    const int wc = wv & 3;
    const int lrow = lane & 15;
    const int kg = lane >> 4;
    const int kgx = kg ^ (lrow & 3);

    f32x4 acc[4][4];
#pragma unroll
    for (int i = 0; i < 4; ++i)
#pragma unroll
        for (int j = 0; j < 4; ++j) acc[i][j] = (f32x4){0.f, 0.f, 0.f, 0.f};

    const size_t rowb = (size_t)K * 2;
    const char* Ab = (const char*)A + (size_t)(bm * 128) * rowb;
    const char* Bb = (const char*)B + (size_t)(bn * 256) * rowb;

    auto STAGE = [&](int bufi, int kk) {
        char* dA = smem + bufi * 24576;
        char* dB = dA + 8192;
        int k2 = kk << 1;
        {
            int s = tid;
            int row = s >> 2, ls = s & 3;
            int gsl = ls ^ (row & 3);
            __builtin_amdgcn_global_load_lds(
                (const __attribute__((address_space(1))) void*)(Ab + (size_t)row * rowb + k2 + gsl * 16),
                (__attribute__((address_space(3))) void*)(dA + s * 16), 16, 0, 0);
        }
#pragma unroll
        for (int j = 0; j < 2; ++j) {
            int s = j * 512 + tid;
            int row = s >> 2, ls = s & 3;
            int gsl = ls ^ (row & 3);
            __builtin_amdgcn_global_load_lds(
                (const __attribute__((address_space(1))) void*)(Bb + (size_t)row * rowb + k2 + gsl * 16),
                (__attribute__((address_space(3))) void*)(dB + s * 16), 16, 0, 0);
        }
    };

    auto COMPUTE = [&](int bufi) {
        const char* Ah = smem + bufi * 24576;
        const char* Bh = Ah + 8192;
        short8 a[4], b[4];
#pragma unroll
        for (int mi = 0; mi < 4; ++mi) {
            int rr = wr * 64 + mi * 16 + lrow;
            a[mi] = *(const short8*)(Ah + rr * 64 + kgx * 16);
        }
#pragma unroll
        for (int ni = 0; ni < 4; ++ni) {
            int rr = wc * 64 + ni * 16 + lrow;
            b[ni] = *(const short8*)(Bh + rr * 64 + kgx * 16);
        }
        __builtin_amdgcn_s_setprio(1);
#pragma unroll
        for (int mi = 0; mi < 4; ++mi)
#pragma unroll
            for (int ni = 0; ni < 4; ++ni)
                acc[mi][ni] = __builtin_amdgcn_mfma_f32_16x16x32_bf16(a[mi], b[ni], acc[mi][ni], 0, 0, 0);
        __builtin_amdgcn_s_setprio(0);
    };

    const int nt = K >> 5;
    STAGE(0, 0);
    STAGE(1, 32);

    for (int t = 0; t < nt; ++t) {
        if (t < nt - 1) asm volatile("s_waitcnt vmcnt(3)" ::: "memory");
        else            asm volatile("s_waitcnt vmcnt(0)" ::: "memory");
        __builtin_amdgcn_s_barrier();
        __builtin_amdgcn_sched_barrier(0);
        if (t + 2 < nt) STAGE((t + 2) % 3, (t + 2) << 5);
        COMPUTE(t % 3);
    }

    float bv[4];
#pragma unroll
    for (int ni = 0; ni < 4; ++ni) {
        int col = bn * 256 + wc * 64 + ni * 16 + lrow;
        bv[ni] = (col < N) ? bias[col] : 0.f;
    }
    LGKM_BARRIER();

    // Epilogue: 2 chunks of 64 rows x 256 cols; NT stores never drained here.
#pragma unroll
    for (int ch = 0; ch < 2; ++ch) {
        if (wr == ch) {
#pragma unroll
            for (int mi = 0; mi < 4; ++mi)
#pragma unroll
                for (int ni = 0; ni < 4; ++ni) {
                    int c = wc * 64 + ni * 16 + lrow;
                    f32x4 v = acc[mi][ni];
#pragma unroll
                    for (int j = 0; j < 4; ++j)
                        Ep[(mi * 16 + kg * 4 + j) * 260 + c] = v[j] + bv[ni];
                }
        }
        LGKM_BARRIER();
#pragma unroll
        for (int rr = 0; rr < 8; ++rr) {
            int rl = wv * 8 + rr;
            int grow = bm * 128 + ch * 64 + rl;
            int gc0 = bn * 256 + lane * 4;
            f32x4 v = *(const f32x4*)&Ep[rl * 260 + lane * 4];
            if (gc0 + 3 < N) {
                __builtin_nontemporal_store(v, (f32x4*)&C[(size_t)grow * N + gc0]);
            } else {
#pragma unroll
                for (int e = 0; e < 4; ++e)
                    if (gc0 + e < N)
                        __builtin_nontemporal_store(v[e], &C[(size_t)grow * N + gc0 + e]);
            }
        }
        if (ch < 1) LGKM_BARRIER();
    }
}

extern "C" void kernel_launch(void* const* d_in, const int* in_sizes, int n_in,
                              void* d_out, int out_size, void* d_ws, size_t ws_size,
                              hipStream_t stream) {
    const int* x    = (const int*)d_in[0];
    const float* emb = (const float*)d_in[1];
    const float* pos = (const float*)d_in[2];
    const float* b1 = (const float*)d_in[3];
    const float* b2 = (const float*)d_in[4];
    const float* b3 = (const float*)d_in[5];
    const float* w2 = (const float*)d_in[6];
    const float* fb2 = (const float*)d_in[7];
    const float* w3 = (const float*)d_in[8];
    const float* fb3 = (const float*)d_in[9];
    const float* wo = (const float*)d_in[10];
    const float* fbo = (const float*)d_in[11];
    float* out = (float*)d_out;

    const int V = 50257;
    const int TN = 197;                 // 256-col tiles for vocab
    const int Vpad = TN * 256;          // 50432

    static bool lds_cap_set = false;
    if (!lds_cap_set) {
        hipFuncSetAttribute((const void*)gemm_bt_v,
                            hipFuncAttributeMaxDynamicSharedMemorySize, 73728);
        lds_cap_set = true;
    }

    // workspace layout
    char* p = (char*)d_ws;
    u16* WO = (u16*)p;  p += (size_t)Vpad * 512 * 2;   // 51.6 MB
    u16* W2 = (u16*)p;  p += (size_t)512 * 512 * 2;
    u16* W3 = (u16*)p;  p += (size_t)512 * 512 * 2;
    u16* Abf = (u16*)p; p += (size_t)4096 * 512 * 2;   // bf16 activations [4096,512]
    u16* Hb = (u16*)p;                                 // bf16 activations [4096,512]

    // fused: embed+pos+leaky1 (blocks 0..63) || cvt WO/W2/W3 (blocks 64..)
    pre_kernel<<<dim3(64 + 2048), dim3(256), 0, stream>>>(
        x, emb, pos, b1, Abf,
        wo, WO, V * 512 / 4, w2, W2, 512 * 512 / 4, w3, W3, 512 * 512 / 4);

    // fc2 + relu -> Hb (bf16): 64x128 tiles, 256 blocks (1/CU)
    gemm_bt_64<<<dim3(64 * 4), dim3(256), 0, stream>>>(Abf, W2, fb2, Hb, 4096, 512, 512, 4);
    // leaky2 -> Abf
    leaky_bf16_kernel<<<dim3(256), dim3(64), 0, stream>>>(Hb, b2, Abf);
    // fc3 + relu -> Hb
    gemm_bt_64<<<dim3(64 * 4), dim3(256), 0, stream>>>(Abf, W3, fb3, Hb, 4096, 512, 512, 4);
    // leaky3 -> Abf
    leaky_bf16_kernel<<<dim3(256), dim3(64), 0, stream>>>(Hb, b3, Abf);
    // vocab projection -> out: 128x256, 8 waves, tri-buffer, bm-major order
    gemm_bt_v<<<dim3(32 * TN), dim3(512), 73728, stream>>>(Abf, WO, fbo, out, 4096, V, 512, 32, TN);
}

// Round 20
// 383.446 us; speedup vs baseline: 1.1731x; 1.1731x over previous
//
#include <hip/hip_runtime.h>

typedef __attribute__((ext_vector_type(8))) short short8;
typedef __attribute__((ext_vector_type(4))) float f32x4;
typedef unsigned short u16;
typedef unsigned int u32;

#define DEVI __device__ __forceinline__

// barrier that does NOT drain vmcnt (keeps NT stores / prefetch in flight)
#define LGKM_BARRIER() do {                                         \
    asm volatile("s_waitcnt lgkmcnt(0)" ::: "memory");              \
    __builtin_amdgcn_sched_barrier(0);                              \
    __builtin_amdgcn_s_barrier();                                   \
    __builtin_amdgcn_sched_barrier(0);                              \
} while (0)

// round-to-nearest-even f32 -> bf16 bits
DEVI u16 f2bf(float f) {
    union { float f; u32 u; } v; v.f = f;
    u32 r = v.u + 0x7FFFu + ((v.u >> 16) & 1u);
    return (u16)(r >> 16);
}
DEVI float bf2f(u16 x) {
    union { u32 u; float f; } v; v.u = ((u32)x) << 16;
    return v.f;
}

// ---- fused pre-kernel: [blocks 0..63] embed+pos+leaky1; [64..] cvt3 ------
__global__ __launch_bounds__(256)
void pre_kernel(const int* __restrict__ x, const float* __restrict__ emb,
                const float* __restrict__ pos, const float* __restrict__ beta,
                u16* __restrict__ Aout,
                const float* __restrict__ wo, u16* __restrict__ WO, int nwo4,
                const float* __restrict__ w2, u16* __restrict__ W2, int nw24,
                const float* __restrict__ w3, u16* __restrict__ W3, int nw34) {
    if (blockIdx.x < 64) {
        __shared__ int xs[128];
        int gtid = blockIdx.x * 256 + threadIdx.x;
        int b = gtid >> 9;
        int h = gtid & 511;
        for (int i = threadIdx.x; i < 128; i += 256) xs[i] = x[i * 32 + b];
        __syncthreads();
        float be = beta[h];
        float mem = 0.f;
        for (int t0 = 0; t0 < 128; t0 += 8) {
            float e[8];
#pragma unroll
            for (int j = 0; j < 8; ++j)
                e[j] = emb[(size_t)xs[t0 + j] * 512 + h] + pos[(t0 + j) * 512 + h];
#pragma unroll
            for (int j = 0; j < 8; ++j) {
                mem = be * mem + e[j];
                Aout[(size_t)((t0 + j) * 32 + b) * 512 + h] = f2bf(mem);
            }
        }
    } else {
        int total = nwo4 + nw24 + nw34;
        int nb = gridDim.x - 64;
        int stride = nb * 256;
        for (int i = (blockIdx.x - 64) * 256 + threadIdx.x; i < total; i += stride) {
            const float* in; u16* out; int j = i;
            if (j < nwo4) { in = wo; out = WO; }
            else if ((j -= nwo4) < nw24) { in = w2; out = W2; }
            else { j -= nw24; in = w3; out = W3; }
            float4 v = reinterpret_cast<const float4*>(in)[j];
            ushort4 o;
            o.x = f2bf(v.x); o.y = f2bf(v.y); o.z = f2bf(v.z); o.w = f2bf(v.w);
            reinterpret_cast<ushort4*>(out)[j] = o;
        }
    }
}

// ---------------- leaky over bf16 input -> bf16 A ----------------
__global__ __launch_bounds__(64)
void leaky_bf16_kernel(const u16* __restrict__ in, const float* __restrict__ beta,
                       u16* __restrict__ Aout) {
    int gtid = blockIdx.x * 64 + threadIdx.x;
    int b = gtid >> 9;
    int h = gtid & 511;
    float be = beta[h];
    float mem = 0.f;
    for (int t0 = 0; t0 < 128; t0 += 8) {
        float v[8];
#pragma unroll
        for (int j = 0; j < 8; ++j)
            v[j] = bf2f(in[(size_t)((t0 + j) * 32 + b) * 512 + h]);
#pragma unroll
        for (int j = 0; j < 8; ++j) {
            mem = be * mem + v[j];
            Aout[(size_t)((t0 + j) * 32 + b) * 512 + h] = f2bf(mem);
        }
    }
}

// ---- 64x128 bf16 GEMM + bias + ReLU -> bf16 out (fc2/fc3) ----------------
__global__ __launch_bounds__(256)
void gemm_bt_64(const u16* __restrict__ A, const u16* __restrict__ B,
                const float* __restrict__ bias, u16* __restrict__ C,
                int M, int N, int K, int tiles_n) {
    __shared__ alignas(16) char smem[32 * 132 * 4];
    u16* As = (u16*)smem;
    u16* Bs = (u16*)(smem + 4096);
    float* Ep = (float*)smem;

    const int tid = threadIdx.x;
    int bm = blockIdx.x / tiles_n;
    int bn = blockIdx.x % tiles_n;
    const int wv = tid >> 6;
    const int lane = tid & 63;
    const int wr = wv >> 1, wc = wv & 1;
    const int lrow = lane & 15;
    const int kg = lane >> 4;
    const int kgx = kg ^ (lrow & 3);

    f32x4 acc[2][4];
#pragma unroll
    for (int i = 0; i < 2; ++i)
#pragma unroll
        for (int j = 0; j < 4; ++j) acc[i][j] = (f32x4){0.f, 0.f, 0.f, 0.f};

    const size_t rowb = (size_t)K * 2;
    const char* Ab = (const char*)A + (size_t)(bm * 64) * rowb;
    const char* Bb = (const char*)B + (size_t)(bn * 128) * rowb;

    float bv[4];
#pragma unroll
    for (int ni = 0; ni < 4; ++ni)
        bv[ni] = bias[bn * 128 + wc * 64 + ni * 16 + lrow];

    for (int k0 = 0; k0 < K; k0 += 32) {
        int k2 = k0 << 1;
        {
            int s = tid;
            int row = s >> 2, ls = s & 3;
            int gsl = ls ^ (row & 3);
            __builtin_amdgcn_global_load_lds(
                (const __attribute__((address_space(1))) void*)(Ab + (size_t)row * rowb + k2 + gsl * 16),
                (__attribute__((address_space(3))) void*)((char*)As + s * 16), 16, 0, 0);
        }
#pragma unroll
        for (int j = 0; j < 2; ++j) {
            int s = j * 256 + tid;
            int row = s >> 2, ls = s & 3;
            int gsl = ls ^ (row & 3);
            __builtin_amdgcn_global_load_lds(
                (const __attribute__((address_space(1))) void*)(Bb + (size_t)row * rowb + k2 + gsl * 16),
                (__attribute__((address_space(3))) void*)((char*)Bs + s * 16), 16, 0, 0);
        }
        __syncthreads();

        short8 a[2], b[4];
#pragma unroll
        for (int mi = 0; mi < 2; ++mi) {
            int rr = wr * 32 + mi * 16 + lrow;
            a[mi] = *(const short8*)((const char*)As + rr * 64 + kgx * 16);
        }
#pragma unroll
        for (int ni = 0; ni < 4; ++ni) {
            int rr = wc * 64 + ni * 16 + lrow;
            b[ni] = *(const short8*)((const char*)Bs + rr * 64 + kgx * 16);
        }
#pragma unroll
        for (int mi = 0; mi < 2; ++mi)
#pragma unroll
            for (int ni = 0; ni < 4; ++ni)
                acc[mi][ni] = __builtin_amdgcn_mfma_f32_16x16x32_bf16(a[mi], b[ni], acc[mi][ni], 0, 0, 0);
        __syncthreads();
    }

#pragma unroll
    for (int ch = 0; ch < 2; ++ch) {
        if (wr == ch) {
#pragma unroll
            for (int mi = 0; mi < 2; ++mi)
#pragma unroll
                for (int ni = 0; ni < 4; ++ni) {
                    int c = wc * 64 + ni * 16 + lrow;
                    f32x4 v = acc[mi][ni];
#pragma unroll
                    for (int j = 0; j < 4; ++j)
                        Ep[(mi * 16 + kg * 4 + j) * 132 + c] = fmaxf(v[j] + bv[ni], 0.f);
                }
        }
        __syncthreads();
#pragma unroll
        for (int rr = 0; rr < 8; ++rr) {
            int rl = wv * 8 + rr;
            int grow = bm * 64 + ch * 32 + rl;
            float lo = Ep[rl * 132 + lane * 2];
            float hi = Ep[rl * 132 + lane * 2 + 1];
            u32 pk = (u32)f2bf(lo) | ((u32)f2bf(hi) << 16);
            *(u32*)((char*)C + ((size_t)grow * N + bn * 128 + lane * 2) * 2) = pk;
        }
        if (ch < 1) __syncthreads();
    }
}

// ---------------- 128x256 bf16 GEMM, BK=32, tri-buffer, 2 blocks/CU (vocab)
// r17-best configuration (383.3us), locked in: bn-major XCD chunks (B one
// HBM touch, A L2/L3-resident), lane-linear staging + granule-XOR source
// permute, frag reads kg^(lrow&3), counted vmcnt(3) tri-buffer, LGKM-only
// epilogue barriers (NT stores drain once at wave exit), [64][260] f32x4
// NT epilogue.
__global__ __launch_bounds__(512, 4)
void gemm_bt_v(const u16* __restrict__ A, const u16* __restrict__ B,
               const float* __restrict__ bias, float* __restrict__ C,
               int M, int N, int K, int tiles_m, int tiles_n) {
    extern __shared__ char smem[];   // 3 x 24576
    float* Ep = (float*)smem;        // [64][260] f32 = 66560 B

    const int tid = threadIdx.x;
    int nwg = tiles_m * tiles_n;
    int q = nwg >> 3, r = nwg & 7;
    int xcd = blockIdx.x & 7, idx = blockIdx.x >> 3;
    int wg = (xcd < r ? xcd * (q + 1) : r * (q + 1) + (xcd - r) * q) + idx;
    int bn = wg / tiles_m;           // bn-major: concurrent blocks share bn
    int bm = wg % tiles_m;

    const int wv = tid >> 6;
    const int lane = tid & 63;
    const int wr = wv >> 2;
    const int wc = wv & 3;
    const int lrow = lane & 15;
    const int kg = lane >> 4;
    const int kgx = kg ^ (lrow & 3);

    f32x4 acc[4][4];
#pragma unroll
    for (int i = 0; i < 4; ++i)
#pragma unroll
        for (int j = 0; j < 4; ++j) acc[i][j] = (f32x4){0.f, 0.f, 0.f, 0.f};

    const size_t rowb = (size_t)K * 2;
    const char* Ab = (const char*)A + (size_t)(bm * 128) * rowb;
    const char* Bb = (const char*)B + (size_t)(bn * 256) * rowb;

    auto STAGE = [&](int bufi, int kk) {
        char* dA = smem + bufi * 24576;
        char* dB = dA + 8192;
        int k2 = kk << 1;
        {
            int s = tid;
            int row = s >> 2, ls = s & 3;
            int gsl = ls ^ (row & 3);
            __builtin_amdgcn_global_load_lds(
                (const __attribute__((address_space(1))) void*)(Ab + (size_t)row * rowb + k2 + gsl * 16),
                (__attribute__((address_space(3))) void*)(dA + s * 16), 16, 0, 0);
        }
#pragma unroll
        for (int j = 0; j < 2; ++j) {
            int s = j * 512 + tid;
            int row = s >> 2, ls = s & 3;
            int gsl = ls ^ (row & 3);
            __builtin_amdgcn_global_load_lds(
                (const __attribute__((address_space(1))) void*)(Bb + (size_t)row * rowb + k2 + gsl * 16),
                (__attribute__((address_space(3))) void*)(dB + s * 16), 16, 0, 0);
        }
    };

    auto COMPUTE = [&](int bufi) {
        const char* Ah = smem + bufi * 24576;
        const char* Bh = Ah + 8192;
        short8 a[4], b[4];
#pragma unroll
        for (int mi = 0; mi < 4; ++mi) {
            int rr = wr * 64 + mi * 16 + lrow;
            a[mi] = *(const short8*)(Ah + rr * 64 + kgx * 16);
        }
#pragma unroll
        for (int ni = 0; ni < 4; ++ni) {
            int rr = wc * 64 + ni * 16 + lrow;
            b[ni] = *(const short8*)(Bh + rr * 64 + kgx * 16);
        }
        __builtin_amdgcn_s_setprio(1);
#pragma unroll
        for (int mi = 0; mi < 4; ++mi)
#pragma unroll
            for (int ni = 0; ni < 4; ++ni)
                acc[mi][ni] = __builtin_amdgcn_mfma_f32_16x16x32_bf16(a[mi], b[ni], acc[mi][ni], 0, 0, 0);
        __builtin_amdgcn_s_setprio(0);
    };

    const int nt = K >> 5;
    STAGE(0, 0);
    STAGE(1, 32);

    for (int t = 0; t < nt; ++t) {
        if (t < nt - 1) asm volatile("s_waitcnt vmcnt(3)" ::: "memory");
        else            asm volatile("s_waitcnt vmcnt(0)" ::: "memory");
        __builtin_amdgcn_s_barrier();
        __builtin_amdgcn_sched_barrier(0);
        if (t + 2 < nt) STAGE((t + 2) % 3, (t + 2) << 5);
        COMPUTE(t % 3);
    }

    float bv[4];
#pragma unroll
    for (int ni = 0; ni < 4; ++ni) {
        int col = bn * 256 + wc * 64 + ni * 16 + lrow;
        bv[ni] = (col < N) ? bias[col] : 0.f;
    }
    LGKM_BARRIER();

    // Epilogue: 2 chunks of 64 rows x 256 cols; NT stores never drained here.
#pragma unroll
    for (int ch = 0; ch < 2; ++ch) {
        if (wr == ch) {
#pragma unroll
            for (int mi = 0; mi < 4; ++mi)
#pragma unroll
                for (int ni = 0; ni < 4; ++ni) {
                    int c = wc * 64 + ni * 16 + lrow;
                    f32x4 v = acc[mi][ni];
#pragma unroll
                    for (int j = 0; j < 4; ++j)
                        Ep[(mi * 16 + kg * 4 + j) * 260 + c] = v[j] + bv[ni];
                }
        }
        LGKM_BARRIER();
#pragma unroll
        for (int rr = 0; rr < 8; ++rr) {
            int rl = wv * 8 + rr;
            int grow = bm * 128 + ch * 64 + rl;
            int gc0 = bn * 256 + lane * 4;
            f32x4 v = *(const f32x4*)&Ep[rl * 260 + lane * 4];
            if (gc0 + 3 < N) {
                __builtin_nontemporal_store(v, (f32x4*)&C[(size_t)grow * N + gc0]);
            } else {
#pragma unroll
                for (int e = 0; e < 4; ++e)
                    if (gc0 + e < N)
                        __builtin_nontemporal_store(v[e], &C[(size_t)grow * N + gc0 + e]);
            }
        }
        if (ch < 1) LGKM_BARRIER();
    }
}

extern "C" void kernel_launch(void* const* d_in, const int* in_sizes, int n_in,
                              void* d_out, int out_size, void* d_ws, size_t ws_size,
                              hipStream_t stream) {
    const int* x    = (const int*)d_in[0];
    const float* emb = (const float*)d_in[1];
    const float* pos = (const float*)d_in[2];
    const float* b1 = (const float*)d_in[3];
    const float* b2 = (const float*)d_in[4];
    const float* b3 = (const float*)d_in[5];
    const float* w2 = (const float*)d_in[6];
    const float* fb2 = (const float*)d_in[7];
    const float* w3 = (const float*)d_in[8];
    const float* fb3 = (const float*)d_in[9];
    const float* wo = (const float*)d_in[10];
    const float* fbo = (const float*)d_in[11];
    float* out = (float*)d_out;

    const int V = 50257;
    const int TN = 197;                 // 256-col tiles for vocab
    const int Vpad = TN * 256;          // 50432

    static bool lds_cap_set = false;
    if (!lds_cap_set) {
        hipFuncSetAttribute((const void*)gemm_bt_v,
                            hipFuncAttributeMaxDynamicSharedMemorySize, 73728);
        lds_cap_set = true;
    }

    // workspace layout
    char* p = (char*)d_ws;
    u16* WO = (u16*)p;  p += (size_t)Vpad * 512 * 2;   // 51.6 MB
    u16* W2 = (u16*)p;  p += (size_t)512 * 512 * 2;
    u16* W3 = (u16*)p;  p += (size_t)512 * 512 * 2;
    u16* Abf = (u16*)p; p += (size_t)4096 * 512 * 2;   // bf16 activations [4096,512]
    u16* Hb = (u16*)p;                                 // bf16 activations [4096,512]

    // fused: embed+pos+leaky1 (blocks 0..63) || cvt WO/W2/W3 (blocks 64..)
    pre_kernel<<<dim3(64 + 2048), dim3(256), 0, stream>>>(
        x, emb, pos, b1, Abf,
        wo, WO, V * 512 / 4, w2, W2, 512 * 512 / 4, w3, W3, 512 * 512 / 4);

    // fc2 + relu -> Hb (bf16): 64x128 tiles, 256 blocks (1/CU)
    gemm_bt_64<<<dim3(64 * 4), dim3(256), 0, stream>>>(Abf, W2, fb2, Hb, 4096, 512, 512, 4);
    // leaky2 -> Abf
    leaky_bf16_kernel<<<dim3(256), dim3(64), 0, stream>>>(Hb, b2, Abf);
    // fc3 + relu -> Hb
    gemm_bt_64<<<dim3(64 * 4), dim3(256), 0, stream>>>(Abf, W3, fb3, Hb, 4096, 512, 512, 4);
    // leaky3 -> Abf
    leaky_bf16_kernel<<<dim3(256), dim3(64), 0, stream>>>(Hb, b3, Abf);
    // vocab projection -> out: 128x256, 8 waves, tri-buffer, bn-major order
    gemm_bt_v<<<dim3(32 * TN), dim3(512), 73728, stream>>>(Abf, WO, fbo, out, 4096, V, 512, 32, TN);
}